// Round 2
// baseline (174.102 us; speedup 1.0000x reference)
//
#include <hip/hip_runtime.h>
#include <math.h>

// Rolling row-pair window version.
//
// Pooled row i consumes input rows 2i-1 .. 2i+2 == row-pairs (i-1, i, i+1)
// (pair p = rows 2p,2p+1; 80 B, 16B-aligned). Processing order i=1,2,3,4,0
// with a single refetch of pair 1 caps live X at 4 pairs = 80 floats
// (vs 100 fully-live in the previous version, which likely spilled).
// Weights are wave-uniform -> forced to SGPRs via readfirstlane so they cost
// zero VGPRs (v_fma_f32 allows one SGPR operand).

#define SREAD(x) __int_as_float(__builtin_amdgcn_readfirstlane(__float_as_int(x)))

__device__ __forceinline__ void load_pair(float (&P)[20], const float* base) {
    const float4* s = (const float4*)base;   // pair base = 80B offset -> 16B aligned
    #pragma unroll
    for (int t = 0; t < 5; ++t) {
        float4 q = s[t];
        P[4 * t + 0] = q.x;
        P[4 * t + 1] = q.y;
        P[4 * t + 2] = q.z;
        P[4 * t + 3] = q.w;
    }
}

// pa: pair i-1 (its 2nd row = row 2i-1), pb: pair i, pc: pair i+1 (1st row = row 2i+2)
__device__ __forceinline__ void pool_row(
    const float (&pa)[20], const float (&pb)[20], const float (&pc)[20],
    const float (&W)[4][9], const float (&Cb)[4], const float (&Dw)[4][4],
    const float Db, const int j2base /* == 0 always; kept for clarity */,
    unsigned& sbits, float& l2)
{
    (void)j2base;
    // 4-row value window; pure SSA copies after SROA (no real instructions).
    float Xw[4][10];
    #pragma unroll
    for (int c = 0; c < 10; ++c) {
        Xw[0][c] = pa[10 + c];   // row 2i-1
        Xw[1][c] = pb[c];        // row 2i
        Xw[2][c] = pb[10 + c];   // row 2i+1
        Xw[3][c] = pc[c];        // row 2i+2
    }
    #pragma unroll
    for (int j = 0; j < 5; ++j) {
        float p0, p1, p2, p3;
        #pragma unroll
        for (int dr = 0; dr < 2; ++dr) {
            #pragma unroll
            for (int dc = 0; dc < 2; ++dc) {
                float a0 = Cb[0], a1 = Cb[1], a2 = Cb[2], a3 = Cb[3];
                #pragma unroll
                for (int kr = 0; kr < 3; ++kr) {
                    #pragma unroll
                    for (int kc = 0; kc < 3; ++kc) {
                        const int cc = (2 * j + dc + kc + 9) % 10;  // compile-time
                        const float xv = Xw[dr + kr][cc];           // tap row 2i+dr+kr-1
                        const int t = kr * 3 + kc;
                        a0 = fmaf(xv, W[0][t], a0);
                        a1 = fmaf(xv, W[1][t], a1);
                        a2 = fmaf(xv, W[2][t], a2);
                        a3 = fmaf(xv, W[3][t], a3);
                    }
                }
                if (dr == 0 && dc == 0) {
                    p0 = a0; p1 = a1; p2 = a2; p3 = a3;
                } else {
                    p0 = fmaxf(p0, a0); p1 = fmaxf(p1, a1);
                    p2 = fmaxf(p2, a2); p3 = fmaxf(p3, a3);
                }
            }
        }
        float z[4];
        #pragma unroll
        for (int kl = 0; kl < 4; ++kl) {
            float zz = Db;
            zz = fmaf(p0, Dw[0][kl], zz);
            zz = fmaf(p1, Dw[1][kl], zz);
            zz = fmaf(p2, Dw[2][kl], zz);
            zz = fmaf(p3, Dw[3][kl], zz);
            z[kl] = zz;
            sbits ^= __float_as_uint(zz);
        }
        // Pairwise products halve the transcendental count; |z0*z1| stays in
        // fp32 normal range.
        l2 += __log2f(fabsf(z[0] * z[1])) + __log2f(fabsf(z[2] * z[3]));
    }
}

__global__ __launch_bounds__(256) void CNN2D_37495064494620_kernel(
    const float* __restrict__ v,
    const float* __restrict__ cw,   // [4,1,3,3]
    const float* __restrict__ cb,   // [4]
    const float* __restrict__ dw,   // [4,1,2,2]
    const float* __restrict__ db,   // [1]
    float* __restrict__ out,        // [2*B]
    int B)
{
    const int b = blockIdx.x * 256 + threadIdx.x;
    if (b >= B) return;

    // Wave-uniform weights -> SGPRs (zero VGPR cost).
    float W[4][9];
    #pragma unroll
    for (int f = 0; f < 4; ++f)
        #pragma unroll
        for (int t = 0; t < 9; ++t)
            W[f][t] = SREAD(cw[f * 9 + t]);
    float Cb[4];
    #pragma unroll
    for (int f = 0; f < 4; ++f) Cb[f] = SREAD(cb[f]);
    float Dw[4][4];
    #pragma unroll
    for (int f = 0; f < 4; ++f)
        #pragma unroll
        for (int t = 0; t < 4; ++t)
            Dw[f][t] = SREAD(dw[f * 4 + t]);
    const float Db = SREAD(db[0]);

    const float* src = v + (size_t)b * 100;

    unsigned sbits = 0u;
    float l2 = 0.0f;

    float P0[20], P1[20], P2[20], P3[20], P4[20], P1b[20];

    load_pair(P0, src + 0);    // rows 0,1
    load_pair(P1, src + 20);   // rows 2,3
    load_pair(P2, src + 40);   // rows 4,5
    load_pair(P3, src + 60);   // prefetch rows 6,7

    pool_row(P0, P1, P2, W, Cb, Dw, Db, 0, sbits, l2);   // i=1 (P1 dies here)

    load_pair(P4, src + 80);   // prefetch rows 8,9

    pool_row(P1, P2, P3, W, Cb, Dw, Db, 0, sbits, l2);   // i=2

    pool_row(P2, P3, P4, W, Cb, Dw, Db, 0, sbits, l2);   // i=3 (P2 dies)

    load_pair(P1b, src + 20);  // refetch rows 2,3 (pc of i=0); prefetched early

    pool_row(P3, P4, P0, W, Cb, Dw, Db, 0, sbits, l2);   // i=4 (P3 dies)

    pool_row(P4, P0, P1b, W, Cb, Dw, Db, 0, sbits, l2);  // i=0

    out[b]     = (sbits & 0x80000000u) ? -1.0f : 1.0f;
    out[B + b] = l2 * 0.69314718055994531f;  // ln2 * sum(log2|z|)
}

extern "C" void kernel_launch(void* const* d_in, const int* in_sizes, int n_in,
                              void* d_out, int out_size, void* d_ws, size_t ws_size,
                              hipStream_t stream) {
    const float* v  = (const float*)d_in[0];
    const float* cw = (const float*)d_in[1];
    const float* cb = (const float*)d_in[2];
    const float* dw = (const float*)d_in[3];
    const float* db = (const float*)d_in[4];
    float* out = (float*)d_out;

    const int B = in_sizes[0] / 100;
    const int grid = (B + 255) / 256;
    CNN2D_37495064494620_kernel<<<grid, 256, 0, stream>>>(v, cw, cb, dw, db, out, B);
}